// Round 1
// baseline (295.887 us; speedup 1.0000x reference)
//
#include <hip/hip_runtime.h>

#define NB 32
#define TT 512
#define SS 5
#define CC 512
#define UU 256
#define NEGV -1e30f

// ---------------------------------------------------------------------------
// Kernel A: per-row logsumexp over C=512; emit em = logits[sym]-lse,
// bl = logits[0]-lse. One wave64 per row, 8 floats/lane.
// Output layout (T, N, S) so the scan kernel reads coalesced across n.
// ---------------------------------------------------------------------------
__global__ __launch_bounds__(256) void row_lse_kernel(
    const float* __restrict__ logits,   // [N][T][S][C]
    const int*   __restrict__ ranges,   // [N][T][S]
    const int*   __restrict__ y,        // [N][U]
    float*       __restrict__ em,       // [T][N][S]
    float*       __restrict__ bl)       // [T][N][S]
{
    int row  = blockIdx.x * 4 + (threadIdx.x >> 6);   // 0 .. N*T*S-1
    int lane = threadIdx.x & 63;
    const float* rowp = logits + (size_t)row * CC;

    float4 v0 = *(const float4*)(rowp + lane * 8);
    float4 v1 = *(const float4*)(rowp + lane * 8 + 4);

    float m = fmaxf(fmaxf(fmaxf(v0.x, v0.y), fmaxf(v0.z, v0.w)),
                    fmaxf(fmaxf(v1.x, v1.y), fmaxf(v1.z, v1.w)));
#pragma unroll
    for (int off = 32; off; off >>= 1)
        m = fmaxf(m, __shfl_xor(m, off));

    float s = __expf(v0.x - m) + __expf(v0.y - m) +
              __expf(v0.z - m) + __expf(v0.w - m) +
              __expf(v1.x - m) + __expf(v1.y - m) +
              __expf(v1.z - m) + __expf(v1.w - m);
#pragma unroll
    for (int off = 32; off; off >>= 1)
        s += __shfl_xor(s, off);

    if (lane == 0) {
        float lse = m + __logf(s);
        int n    = row / (TT * SS);
        int rem  = row - n * (TT * SS);
        int t    = rem / SS;
        int sidx = rem - t * SS;
        int r    = ranges[row];          // lb + sidx
        int sym  = y[n * UU + r];
        int w    = (t * NB + n) * SS + sidx;
        em[w] = rowp[sym] - lse;         // L1-hot: row just read by this wave
        bl[w] = rowp[0]   - lse;
    }
}

// ---------------------------------------------------------------------------
// Kernel B: serial lattice scan. One lane per batch item (32 active lanes).
// State kept in named registers (no runtime-indexed arrays -> no scratch).
// ---------------------------------------------------------------------------
__device__ __forceinline__ float lse2f(float x, float y) {
    float m = fmaxf(x, y);
    float d = fabsf(x - y);
    return m + __logf(1.0f + __expf(-d));
}

__global__ __launch_bounds__(64) void scan_kernel(
    const float* __restrict__ em,       // [T][N][S]
    const float* __restrict__ bl,       // [T][N][S]
    const int*   __restrict__ ranges,   // [N][T][S]
    float*       __restrict__ out)      // [2]
{
    int lane = threadIdx.x;
    float pl = 0.0f, pm = 0.0f;

    if (lane < NB) {
        int n = lane;
        float al0 = 0.0f, al1 = NEGV, al2 = NEGV, al3 = NEGV, al4 = NEGV;
        float am0 = 0.0f, am1 = NEGV, am2 = NEGV, am3 = NEGV, am4 = NEGV;
        int lb_prev = ranges[n * TT * SS];          // ranges[n][0][0]

        for (int t = 0; t < TT; ++t) {
            const float* ep = em + (t * NB + n) * SS;
            const float* bp = bl + (t * NB + n) * SS;
            float e0 = ep[0], e1 = ep[1], e2 = ep[2], e3 = ep[3];

            // emit chain (sequential in s; lse & max chains are independent ILP)
            al1 = lse2f(al1, al0 + e0);
            am1 = fmaxf(am1, am0 + e0);
            al2 = lse2f(al2, al1 + e1);
            am2 = fmaxf(am2, am1 + e1);
            al3 = lse2f(al3, al2 + e2);
            am3 = fmaxf(am3, am2 + e2);
            al4 = lse2f(al4, al3 + e3);
            am4 = fmaxf(am4, am3 + e3);

            if (t < TT - 1) {
                float b0 = bp[0], b1 = bp[1], b2 = bp[2], b3 = bp[3], b4 = bp[4];
                int lb_next = ranges[(n * TT + t + 1) * SS];
                int d = lb_next - lb_prev;          // in {0,1} by construction
                lb_prev = lb_next;
                bool sh = (d != 0);

                float nl0 = sh ? al1 + b1 : al0 + b0;
                float nl1 = sh ? al2 + b2 : al1 + b1;
                float nl2 = sh ? al3 + b3 : al2 + b2;
                float nl3 = sh ? al4 + b4 : al3 + b3;
                float nl4 = sh ? NEGV     : al4 + b4;
                float nm0 = sh ? am1 + b1 : am0 + b0;
                float nm1 = sh ? am2 + b2 : am1 + b1;
                float nm2 = sh ? am3 + b3 : am2 + b2;
                float nm3 = sh ? am4 + b4 : am3 + b3;
                float nm4 = sh ? NEGV     : am4 + b4;
                al0 = nl0; al1 = nl1; al2 = nl2; al3 = nl3; al4 = nl4;
                am0 = nm0; am1 = nm1; am2 = nm2; am3 = nm3; am4 = nm4;
            }
        }
        pl = -al4;
        pm = -am4;
    }

    // sum across the full wave (lanes >= 32 contribute 0)
#pragma unroll
    for (int off = 32; off; off >>= 1) {
        pl += __shfl_xor(pl, off);
        pm += __shfl_xor(pm, off);
    }
    if (lane == 0) {
        out[0] = pl;   // pruned_loss
        out[1] = pm;   // one_best_loss
    }
}

extern "C" void kernel_launch(void* const* d_in, const int* in_sizes, int n_in,
                              void* d_out, int out_size, void* d_ws, size_t ws_size,
                              hipStream_t stream) {
    const float* logits = (const float*)d_in[0];
    const int*   ranges = (const int*)d_in[1];
    const int*   y      = (const int*)d_in[2];
    // d_in[3] = x_lens, unused (reference ignores it; all == T)

    float* em  = (float*)d_ws;                 // T*N*S floats
    float* bl  = em + (size_t)TT * NB * SS;    // T*N*S floats
    float* out = (float*)d_out;

    int rows = NB * TT * SS;                   // 81920
    hipLaunchKernelGGL(row_lse_kernel, dim3(rows / 4), dim3(256), 0, stream,
                       logits, ranges, y, em, bl);
    hipLaunchKernelGGL(scan_kernel, dim3(1), dim3(64), 0, stream,
                       em, bl, ranges, out);
}

// Round 2
// 74.342 us; speedup vs baseline: 3.9801x; 3.9801x over previous
//
#include <hip/hip_runtime.h>

#define NB 32
#define TT 512
#define SS 5
#define CC 512
#define UU 256
#define NEGV -1e30f
#define LCH 16              // chunk length (timesteps)
#define NCH (TT / LCH)      // 32 chunks
#define CSTRIDE (2 * NB * 25)   // floats between chunk c and c+1 in mats

// ---------------------------------------------------------------------------
// Kernel A: per-row logsumexp over C=512; emit em = logits[sym]-lse,
// bl = logits[0]-lse. One wave64 per row, 8 floats/lane.
// Output layout (T, N, S) so the scan kernels read coalesced across n.
// ---------------------------------------------------------------------------
__global__ __launch_bounds__(256) void row_lse_kernel(
    const float* __restrict__ logits,   // [N][T][S][C]
    const int*   __restrict__ ranges,   // [N][T][S]
    const int*   __restrict__ y,        // [N][U]
    float*       __restrict__ em,       // [T][N][S]
    float*       __restrict__ bl)       // [T][N][S]
{
    int row  = blockIdx.x * 4 + (threadIdx.x >> 6);   // 0 .. N*T*S-1
    int lane = threadIdx.x & 63;
    const float* rowp = logits + (size_t)row * CC;

    float4 v0 = *(const float4*)(rowp + lane * 8);
    float4 v1 = *(const float4*)(rowp + lane * 8 + 4);

    float m = fmaxf(fmaxf(fmaxf(v0.x, v0.y), fmaxf(v0.z, v0.w)),
                    fmaxf(fmaxf(v1.x, v1.y), fmaxf(v1.z, v1.w)));
#pragma unroll
    for (int off = 32; off; off >>= 1)
        m = fmaxf(m, __shfl_xor(m, off));

    float s = __expf(v0.x - m) + __expf(v0.y - m) +
              __expf(v0.z - m) + __expf(v0.w - m) +
              __expf(v1.x - m) + __expf(v1.y - m) +
              __expf(v1.z - m) + __expf(v1.w - m);
#pragma unroll
    for (int off = 32; off; off >>= 1)
        s += __shfl_xor(s, off);

    if (lane == 0) {
        float lse = m + __logf(s);
        int n    = row / (TT * SS);
        int rem  = row - n * (TT * SS);
        int t    = rem / SS;
        int sidx = rem - t * SS;
        int r    = ranges[row];          // lb + sidx
        int sym  = y[n * UU + r];
        int w    = (t * NB + n) * SS + sidx;
        em[w] = rowp[sym] - lse;         // L1-hot: row just read by this wave
        bl[w] = rowp[0]   - lse;
    }
}

// ---------------------------------------------------------------------------
// Semiring helpers
// ---------------------------------------------------------------------------
__device__ __forceinline__ float lse2f(float x, float y) {
    float m = fmaxf(x, y);
    float d = fabsf(x - y);
    return m + __logf(1.0f + __expf(-d));
}

template <bool MAXSEM>
__device__ __forceinline__ float combf(float x, float y) {
    return MAXSEM ? fmaxf(x, y) : lse2f(x, y);
}

// ---------------------------------------------------------------------------
// Stage 1: each lane pushes basis vector e_j through chunk c for batch item n,
// producing column j of the chunk's 5x5 semiring matrix.
// grid = (NCH, 2 semirings), block = (32 n, 5 j).
// mats layout: [c][sem][n][j][s]
// ---------------------------------------------------------------------------
template <bool MAXSEM>
__device__ __forceinline__ void chunk_scan(
    const float* __restrict__ em, const float* __restrict__ bl,
    const int* __restrict__ ranges, int n, int j, int c,
    float* __restrict__ outp)
{
    float v0 = (j == 0) ? 0.0f : NEGV;
    float v1 = (j == 1) ? 0.0f : NEGV;
    float v2 = (j == 2) ? 0.0f : NEGV;
    float v3 = (j == 3) ? 0.0f : NEGV;
    float v4 = (j == 4) ? 0.0f : NEGV;

    int t0 = c * LCH;
    int lb_prev = ranges[(n * TT + t0) * SS];

    for (int i = 0; i < LCH; ++i) {
        int t = t0 + i;
        const float* ep = em + (t * NB + n) * SS;
        float e0 = ep[0], e1 = ep[1], e2 = ep[2], e3 = ep[3];

        v1 = combf<MAXSEM>(v1, v0 + e0);
        v2 = combf<MAXSEM>(v2, v1 + e1);
        v3 = combf<MAXSEM>(v3, v2 + e2);
        v4 = combf<MAXSEM>(v4, v3 + e3);

        if (t < TT - 1) {
            const float* bp = bl + (t * NB + n) * SS;
            float b0 = bp[0], b1 = bp[1], b2 = bp[2], b3 = bp[3], b4 = bp[4];
            int lb_next = ranges[(n * TT + t + 1) * SS];
            bool sh = (lb_next != lb_prev);   // delta in {0,1}
            lb_prev = lb_next;

            float n0 = sh ? v1 + b1 : v0 + b0;
            float n1 = sh ? v2 + b2 : v1 + b1;
            float n2 = sh ? v3 + b3 : v2 + b2;
            float n3 = sh ? v4 + b4 : v3 + b3;
            float n4 = sh ? NEGV    : v4 + b4;
            v0 = n0; v1 = n1; v2 = n2; v3 = n3; v4 = n4;
        }
    }
    outp[0] = v0; outp[1] = v1; outp[2] = v2; outp[3] = v3; outp[4] = v4;
}

__global__ __launch_bounds__(160) void scan_stage1(
    const float* __restrict__ em, const float* __restrict__ bl,
    const int* __restrict__ ranges, float* __restrict__ mats)
{
    int n = threadIdx.x;          // 0..31
    int j = threadIdx.y;          // 0..4
    int c = blockIdx.x;           // 0..NCH-1
    int sem = blockIdx.y;         // 0 = lse, 1 = max

    float* outp = mats + ((size_t)(c * 2 + sem) * NB + n) * 25 + j * 5;
    if (sem == 0)
        chunk_scan<false>(em, bl, ranges, n, j, c, outp);
    else
        chunk_scan<true>(em, bl, ranges, n, j, c, outp);
}

// ---------------------------------------------------------------------------
// Stage 2: per (n, semiring), compose the 32 chunk matrices as serial
// mat-vec products starting from v = e0; double-buffered register prefetch.
// block = 128: wave 0 = lse (lanes 0..31 active), wave 1 = max.
// ---------------------------------------------------------------------------
#define LOAD25(dst, src)                 \
    _Pragma("unroll")                    \
    for (int _i = 0; _i < 25; ++_i) dst[_i] = (src)[_i];

template <bool MAXSEM>
__device__ __forceinline__ void matvec(const float m[25],
    float& v0, float& v1, float& v2, float& v3, float& v4)
{
    // M[s][j] = m[j*5+s];  v_new[s] = comb_j (M[s][j] + v[j])
    float r0 = combf<MAXSEM>(combf<MAXSEM>(combf<MAXSEM>(combf<MAXSEM>(
                 m[0] + v0, m[5] + v1), m[10] + v2), m[15] + v3), m[20] + v4);
    float r1 = combf<MAXSEM>(combf<MAXSEM>(combf<MAXSEM>(combf<MAXSEM>(
                 m[1] + v0, m[6] + v1), m[11] + v2), m[16] + v3), m[21] + v4);
    float r2 = combf<MAXSEM>(combf<MAXSEM>(combf<MAXSEM>(combf<MAXSEM>(
                 m[2] + v0, m[7] + v1), m[12] + v2), m[17] + v3), m[22] + v4);
    float r3 = combf<MAXSEM>(combf<MAXSEM>(combf<MAXSEM>(combf<MAXSEM>(
                 m[3] + v0, m[8] + v1), m[13] + v2), m[18] + v3), m[23] + v4);
    float r4 = combf<MAXSEM>(combf<MAXSEM>(combf<MAXSEM>(combf<MAXSEM>(
                 m[4] + v0, m[9] + v1), m[14] + v2), m[19] + v3), m[24] + v4);
    v0 = r0; v1 = r1; v2 = r2; v3 = r3; v4 = r4;
}

template <bool MAXSEM>
__device__ __forceinline__ float compose_all(const float* __restrict__ base)
{
    float v0 = 0.0f, v1 = NEGV, v2 = NEGV, v3 = NEGV, v4 = NEGV;
    float mA[25], mB[25];
    LOAD25(mA, base);
#pragma unroll 4
    for (int c = 0; c < NCH; c += 2) {
        if (c + 1 < NCH) { LOAD25(mB, base + (size_t)(c + 1) * CSTRIDE); }
        matvec<MAXSEM>(mA, v0, v1, v2, v3, v4);
        if (c + 2 < NCH) { LOAD25(mA, base + (size_t)(c + 2) * CSTRIDE); }
        if (c + 1 < NCH) { matvec<MAXSEM>(mB, v0, v1, v2, v3, v4); }
    }
    return -v4;
}

__global__ __launch_bounds__(128) void scan_stage2(
    const float* __restrict__ mats, float* __restrict__ out)
{
    int sem  = threadIdx.x >> 6;       // wave 0: lse, wave 1: max
    int lane = threadIdx.x & 63;
    bool active = lane < NB;
    int nn = active ? lane : 0;

    const float* base = mats + ((size_t)sem * NB + nn) * 25;
    float p;
    if (sem == 0) p = compose_all<false>(base);
    else          p = compose_all<true>(base);
    if (!active) p = 0.0f;

#pragma unroll
    for (int off = 16; off; off >>= 1)
        p += __shfl_xor(p, off);

    if (lane == 0) out[sem];    // placeholder to keep structure clear
    if (lane == 0) out[sem] = p;   // out[0]=pruned (lse), out[1]=one_best (max)
}

extern "C" void kernel_launch(void* const* d_in, const int* in_sizes, int n_in,
                              void* d_out, int out_size, void* d_ws, size_t ws_size,
                              hipStream_t stream) {
    const float* logits = (const float*)d_in[0];
    const int*   ranges = (const int*)d_in[1];
    const int*   y      = (const int*)d_in[2];
    // d_in[3] = x_lens, unused (reference ignores it; all == T)

    float* em   = (float*)d_ws;                     // T*N*S floats
    float* bl   = em + (size_t)TT * NB * SS;        // T*N*S floats
    float* mats = bl + (size_t)TT * NB * SS;        // NCH*2*NB*25 floats
    float* out  = (float*)d_out;

    int rows = NB * TT * SS;                        // 81920
    hipLaunchKernelGGL(row_lse_kernel, dim3(rows / 4), dim3(256), 0, stream,
                       logits, ranges, y, em, bl);
    hipLaunchKernelGGL(scan_stage1, dim3(NCH, 2), dim3(32, 5), 0, stream,
                       em, bl, ranges, mats);
    hipLaunchKernelGGL(scan_stage2, dim3(1), dim3(128), 0, stream,
                       mats, out);
}